// Round 7
// baseline (137.076 us; speedup 1.0000x reference)
//
#include <hip/hip_runtime.h>

// Batched 2D db4 DWT (pywt dwt2, mode='symmetric') over [8,32,512,512] f32.
// Output [4, 8, 32, 259, 259] f32 (LL, LH, HL, HH).
//
//   y[o] = sum_k ext[2o+1+k] * G[k],  G[k] = F[7-k]
//   ext index j -> src:  j<7 -> 6-j ; j<=518 -> j-7 ; else 1030-j
//
// v7 = v6 (register-streaming walker, depth-1 prefetch) +
//  (a) block-level interior/edge split: interior blocks have compile-time
//      MODE=0 (no exec-mask window selects); edge blocks are wave-uniform
//      per side (boundary 5632 = 88 waves exactly).
//  (b) non-temporal output stores: output (275 MB) no longer evicts the
//      input (256 MB) from the 256 MB L3 -> input re-reads stay L3-hits.

namespace {

constexpr int N    = 512;
constexpr int HO   = 259;
constexpr int NBC  = 256;
constexpr int TOH  = 12;                     // output rows per strip
constexpr int NS   = 22;                     // strips (22*12 = 264 >= 259)
constexpr int MIDR = 2 * TOH + 6;            // 30 mid rows per strip

constexpr int NCGI   = 63;                   // interior 4-col groups (cg = 1..63)
constexpr int IITEMS = NBC * NS * NCGI;      // 354,816
constexpr int IBLK   = IITEMS / 256;         // 1386 (exact)
constexpr int EITEMS = NBC * NS * 2;         // 11,264
constexpr int EBLK   = EITEMS / 256;         // 44 (exact)
constexpr int EHALF  = EITEMS / 2;           // 5632 (= 88 waves)

typedef float f4 __attribute__((ext_vector_type(4)));
typedef f4 __attribute__((aligned(4))) f4u;

__device__ constexpr float GL[8] = {
     0.23037781330885523f,  0.7148465705525415f,   0.6308807679295904f,
    -0.02798376941698385f, -0.18703481171888114f,  0.030841381835986965f,
     0.032883011666982945f,-0.010597401784997278f};
__device__ constexpr float GH[8] = {
    -0.010597401784997278f,-0.032883011666982945f, 0.030841381835986965f,
     0.18703481171888114f, -0.02798376941698385f, -0.6308807679295904f,
     0.7148465705525415f,  -0.23037781330885523f};

// Tap f -> index into the 16-float window loaded from base ab.
// interior (ab = 8cg-8): tap f = win[2+f]
// cg==0   (ab = 0)     : ext[1+f]   -> LMAP
// cg==64  (ab = 496)   : ext[513+f] -> RMAP
__device__ constexpr int LMAP[14] = {5,4,3,2,1,0,0,1,2,3,4,5,6,7};
__device__ constexpr int RMAP[14] = {10,11,12,13,14,15,15,14,13,12,11,10,9,8};

__device__ __forceinline__ int ext_row(int j) {
    int v = j - 7;
    v = (j < 7)     ? (6 - j)         : v;
    v = (j > N + 6) ? (2 * N + 6 - j) : v;
    return v;
}

template <int MODE>
__device__ __forceinline__ void hconv16(const f4& A, const f4& B, const f4& C,
                                        const f4& D, f4& lo, f4& hi) {
    const float win[16] = {A.x,A.y,A.z,A.w, B.x,B.y,B.z,B.w,
                           C.x,C.y,C.z,C.w, D.x,D.y,D.z,D.w};
    float v[14];
    if constexpr (MODE == 0) {
        #pragma unroll
        for (int f = 0; f < 14; ++f) v[f] = win[2 + f];
    } else if constexpr (MODE < 0) {
        #pragma unroll
        for (int f = 0; f < 14; ++f) v[f] = win[LMAP[f]];
    } else {
        #pragma unroll
        for (int f = 0; f < 14; ++f) v[f] = win[RMAP[f]];
    }
    #pragma unroll
    for (int o = 0; o < 4; ++o) {
        float l = 0.f, h = 0.f;
        #pragma unroll
        for (int k = 0; k < 8; ++k) {
            l = fmaf(v[2 * o + k], GL[k], l);
            h = fmaf(v[2 * o + k], GH[k], h);
        }
        lo[o] = l; hi[o] = h;
    }
}

template <int MODE>
__device__ __forceinline__ void strip_body(const float* __restrict__ img,
                                           float* __restrict__ obase,
                                           size_t sub, int eh0, int st,
                                           int c0, int ab) {
    // pending accumulators: P[slot][0..3] = ll, lh, hl, hh
    f4 P[4][4];
    #pragma unroll
    for (int s = 0; s < 4; ++s)
        #pragma unroll
        for (int q = 0; q < 4; ++q) P[s][q] = (f4){0.f, 0.f, 0.f, 0.f};

    f4 b0a, b0b, b0c, b0d, b1a, b1b, b1c, b1d;

#define PRE(rn_, A_, B_, C_, D_) do {                                         \
    const float* rp_ = img + (size_t)ext_row(eh0 + (rn_)) * N + ab;           \
    A_ = *(const f4*)(rp_);      B_ = *(const f4*)(rp_ + 4);                  \
    C_ = *(const f4*)(rp_ + 8);  D_ = *(const f4*)(rp_ + 12);                 \
} while (0)

#define UPD(r_, uo_) do { if ((uo_) >= 0 && (uo_) < TOH) {                    \
    const int kk_ = (r_) - 2 * (uo_);                                         \
    const int sl_ = (uo_) & 3;                                                \
    const float gl_ = GL[kk_], gh_ = GH[kk_];                                 \
    P[sl_][0] += lo * gl_;  P[sl_][1] += lo * gh_;                            \
    P[sl_][2] += hi * gl_;  P[sl_][3] += hi * gh_;                            \
} } while (0)

#define FIN(r_) do {                                                          \
    const int uo_ = ((r_) - 7) / 2;                                           \
    if (uo_ >= 0 && uo_ < TOH) {                                              \
        const int sl_ = uo_ & 3;                                              \
        const int ho_ = st * TOH + uo_;                                       \
        if (ho_ < HO) {                                                       \
            const size_t p_ = (size_t)ho_ * HO + c0;                          \
            if constexpr (MODE != 1) {                                        \
                __builtin_nontemporal_store(P[sl_][0], (f4u*)(obase + p_));   \
                __builtin_nontemporal_store(P[sl_][1], (f4u*)(obase + sub + p_)); \
                __builtin_nontemporal_store(P[sl_][2], (f4u*)(obase + 2 * sub + p_)); \
                __builtin_nontemporal_store(P[sl_][3], (f4u*)(obase + 3 * sub + p_)); \
            } else {                                                          \
                _Pragma("unroll")                                             \
                for (int o = 0; o < 3; ++o) {                                 \
                    __builtin_nontemporal_store(P[sl_][0][o], obase + p_ + o);\
                    __builtin_nontemporal_store(P[sl_][1][o], obase + sub + p_ + o); \
                    __builtin_nontemporal_store(P[sl_][2][o], obase + 2 * sub + p_ + o); \
                    __builtin_nontemporal_store(P[sl_][3][o], obase + 3 * sub + p_ + o); \
                }                                                             \
            }                                                                 \
        }                                                                     \
        P[sl_][0] = (f4){0.f,0.f,0.f,0.f};  P[sl_][1] = (f4){0.f,0.f,0.f,0.f};\
        P[sl_][2] = (f4){0.f,0.f,0.f,0.f};  P[sl_][3] = (f4){0.f,0.f,0.f,0.f};\
    }                                                                         \
} while (0)

#define ROW(r_, CA_, CB_, CC_, CD_, NA_, NB_, NC_, ND_) do {                  \
    if ((r_) + 1 < MIDR) PRE((r_) + 1, NA_, NB_, NC_, ND_);                   \
    f4 lo, hi;                                                                \
    hconv16<MODE>(CA_, CB_, CC_, CD_, lo, hi);                                \
    if (((r_) & 1) == 0) {                                                    \
        UPD(r_, (r_) / 2);     UPD(r_, (r_) / 2 - 1);                         \
        UPD(r_, (r_) / 2 - 2); UPD(r_, (r_) / 2 - 3);                         \
    } else {                                                                  \
        UPD(r_, ((r_) - 1) / 2); UPD(r_, ((r_) - 3) / 2);                     \
        UPD(r_, ((r_) - 5) / 2); UPD(r_, ((r_) - 7) / 2);                     \
        FIN(r_);                                                              \
    }                                                                         \
} while (0)

#define ROW_E(r_) ROW(r_, b0a,b0b,b0c,b0d, b1a,b1b,b1c,b1d)
#define ROW_O(r_) ROW(r_, b1a,b1b,b1c,b1d, b0a,b0b,b0c,b0d)

    PRE(0, b0a, b0b, b0c, b0d);
    ROW_E(0);  ROW_O(1);  ROW_E(2);  ROW_O(3);  ROW_E(4);  ROW_O(5);
    ROW_E(6);  ROW_O(7);  ROW_E(8);  ROW_O(9);  ROW_E(10); ROW_O(11);
    ROW_E(12); ROW_O(13); ROW_E(14); ROW_O(15); ROW_E(16); ROW_O(17);
    ROW_E(18); ROW_O(19); ROW_E(20); ROW_O(21); ROW_E(22); ROW_O(23);
    ROW_E(24); ROW_O(25); ROW_E(26); ROW_O(27); ROW_E(28); ROW_O(29);

#undef ROW_E
#undef ROW_O
#undef ROW
#undef FIN
#undef UPD
#undef PRE
}

__global__ __launch_bounds__(256)
void dwt2_db4_v7(const float* __restrict__ x, float* __restrict__ out) {
    const size_t sub = (size_t)NBC * HO * HO;
    if (blockIdx.x < (unsigned)IBLK) {
        const int id   = blockIdx.x * 256 + threadIdx.x;
        const int cg   = 1 + id % NCGI;            // 1..63: interior
        const int rest = id / NCGI;
        const int st   = rest % NS;
        const int bc   = rest / NS;
        const float* __restrict__ img = x + (size_t)bc * (N * N);
        float* __restrict__ obase = out + (size_t)bc * (HO * HO);
        strip_body<0>(img, obase, sub, 2 * (st * TOH) + 1, st, 4 * cg, 8 * cg - 8);
    } else {
        const int eid  = (blockIdx.x - IBLK) * 256 + threadIdx.x;
        const int side = eid / EHALF;              // wave-uniform (5632 % 64 == 0)
        const int rest = eid % EHALF;
        const int st   = rest % NS;
        const int bc   = rest / NS;
        const float* __restrict__ img = x + (size_t)bc * (N * N);
        float* __restrict__ obase = out + (size_t)bc * (HO * HO);
        const int eh0 = 2 * (st * TOH) + 1;
        if (side == 0) strip_body<-1>(img, obase, sub, eh0, st, 0,   0);
        else           strip_body< 1>(img, obase, sub, eh0, st, 256, N - 16);
    }
}

} // namespace

extern "C" void kernel_launch(void* const* d_in, const int* in_sizes, int n_in,
                              void* d_out, int out_size, void* d_ws, size_t ws_size,
                              hipStream_t stream) {
    const float* x = (const float*)d_in[0];
    float* out = (float*)d_out;
    dwt2_db4_v7<<<IBLK + EBLK, 256, 0, stream>>>(x, out);  // 1430 blocks
}